// Round 4
// baseline (215.784 us; speedup 1.0000x reference)
//
#include <hip/hip_runtime.h>
#include <hip/hip_cooperative_groups.h>
#include <math.h>

namespace cg = cooperative_groups;

// Problem constants
#define R_   1152
#define C_   10
#define D_   16
#define I_   8
#define B_   256
#define N_   160      // C_*D_ (n = c*16+d)
#define K_   9216     // R_*I_ (k = r*8+i)
#define KS_  32       // K-split across blocks
#define KC_  288      // K_/KS_ per block
#define KW_  72       // per-wave k slice (KC_/4)

#define NBLK 256
#define NTHR 256
#define TOT  (NBLK * NTHR)   // 65536 threads

// workspace layout (float offsets); shared by coop and fallback paths
#define OFF_WT    0                      // 1,474,560  WT[k][n]
#define OFF_WSUM  1474560                //    92,160  Wsum[r][c][i]
#define OFF_TT    (OFF_WSUM + 92160)     // 2,949,120  tT[c][b][r]
#define OFF_V     (OFF_TT + 2949120)     //    40,960  v[b][n]
#define OFF_BIJ   (OFF_V + 40960)        //   184,320  bij[r][n]
#define OFF_NMAX  (OFF_BIJ + 184320)     //       160  (fallback path only)
#define OFF_NSUM  (OFF_NMAX + 160)       //       160
#define OFF_CNT   (OFF_NSUM + 160)       //        64  (ints; lastblock counters)
#define OFF_PART  (OFF_CNT + 64)         // 1,310,720  partials[ks][b][n]

// ===========================================================================
// Shared device phases (used by the cooperative mega-kernel)
// ===========================================================================

__device__ void prep_phase(const float* __restrict__ W, float* __restrict__ Wsum,
                           float* __restrict__ WT, int gid) {
    // Wsum[r,c,i] = sum_d W[r,c,d,i]   (92160 items, grid-stride)
    for (int idx = gid; idx < 92160; idx += TOT) {
        int r = idx / (C_ * I_);
        int rem = idx % (C_ * I_);
        int c = rem / I_;
        int i = rem % I_;
        const float* p = W + (size_t)r * (C_ * D_ * I_) + c * (D_ * I_) + i;
        float s = 0.0f;
#pragma unroll
        for (int d = 0; d < D_; ++d) s += p[d * I_];
        Wsum[idx] = s;
    }
    // WT[k][n] = W[r][n][i]  (368640 float4 items, grid-stride)
    for (int q = gid; q < 368640; q += TOT) {
        int k = q / (N_ / 4);
        int n4 = (q % (N_ / 4)) * 4;
        int r = k >> 3, i = k & 7;
        const float* wp = W + (size_t)r * (C_ * D_ * I_) + n4 * I_ + i;
        float4 o;
        o.x = wp[0]; o.y = wp[8]; o.z = wp[16]; o.w = wp[24];
        ((float4*)WT)[q] = o;
    }
}

// tT[c][b][r] = sum_i Wsum[r,c,i] * u[b,r,i]
__device__ void t_phase(const float* __restrict__ u, const float* __restrict__ Wsum,
                        float* __restrict__ tT, int gid) {
    for (int idx = gid; idx < B_ * R_; idx += TOT) {
        int r = idx % R_;
        int b = idx / R_;
        const float4* up = (const float4*)(u + (size_t)idx * I_);
        float4 a0 = up[0], a1 = up[1];
        const float* wp = Wsum + (size_t)r * (C_ * I_);
        float outv[C_];
#pragma unroll
        for (int c = 0; c < C_; ++c) {
            const float4* w4 = (const float4*)(wp + c * I_);
            float4 w0 = w4[0], w1 = w4[1];
            outv[c] = a0.x * w0.x + a0.y * w0.y + a0.z * w0.z + a0.w * w0.w
                    + a1.x * w1.x + a1.y * w1.y + a1.z * w1.z + a1.w * w1.w;
        }
#pragma unroll
        for (int c = 0; c < C_; ++c)
            tT[((size_t)c * B_ + b) * R_ + r] = outv[c];
    }
}

// GEMM phase, 2 b-tiles per block (bt0 and bt0+8, same ks -> WT loads shared).
// Lastblock (threadfence-reduction) finalize: 32nd arriver per bt reduces the
// 32 partials slices + squash -> dst.
__device__ void gemm_phase2(const float* __restrict__ u, const float* __restrict__ WT,
                            float* __restrict__ partials, float* __restrict__ red,
                            int* __restrict__ cnt, float* __restrict__ dst, float scale,
                            int bid, int tid, int* __restrict__ flags) {
    int wave = tid >> 6, lane = tid & 63;
    int ng = lane & 15, bg = lane >> 4;
    int ks = bid & 31;
    int bt0 = bid >> 5;                 // 0..7; second tile is bt0+8
    int kbase = ks * KC_ + wave * KW_;
    int n0 = ng * 10;

    float acc[2][4][10];
#pragma unroll
    for (int t = 0; t < 2; ++t)
#pragma unroll
        for (int m = 0; m < 4; ++m)
#pragma unroll
            for (int j = 0; j < 10; ++j) acc[t][m][j] = 0.0f;

    const float* ur[2][4];
#pragma unroll
    for (int t = 0; t < 2; ++t)
#pragma unroll
        for (int m = 0; m < 4; ++m)
            ur[t][m] = u + (size_t)((bt0 + 8 * t) * 16 + bg * 4 + m) * K_;

    for (int kk = 0; kk < KW_; kk += 4) {
        int k = kbase + kk;
        float ua[2][4][4];
#pragma unroll
        for (int t = 0; t < 2; ++t)
#pragma unroll
            for (int m = 0; m < 4; ++m) {
                float4 tmp = *(const float4*)(ur[t][m] + k);
                ua[t][m][0] = tmp.x; ua[t][m][1] = tmp.y;
                ua[t][m][2] = tmp.z; ua[t][m][3] = tmp.w;
            }
#pragma unroll
        for (int t4 = 0; t4 < 4; ++t4) {
            const float* wrow = WT + (size_t)(k + t4) * N_ + n0;
            float w[10];
#pragma unroll
            for (int j = 0; j < 10; j += 2) {
                float2 ww = *(const float2*)(wrow + j);
                w[j] = ww.x; w[j + 1] = ww.y;
            }
#pragma unroll
            for (int t = 0; t < 2; ++t)
#pragma unroll
                for (int m = 0; m < 4; ++m)
#pragma unroll
                    for (int j = 0; j < 10; ++j)
                        acc[t][m][j] = fmaf(ua[t][m][t4], w[j], acc[t][m][j]);
        }
    }

    // per-tile LDS cross-wave reduce + partials store
#pragma unroll
    for (int t = 0; t < 2; ++t) {
        int bt = bt0 + 8 * t;
        __syncthreads();
#pragma unroll
        for (int m = 0; m < 4; ++m)
#pragma unroll
            for (int j = 0; j < 10; ++j)
                red[wave * 2560 + (bg * 4 + m) * N_ + n0 + j] = acc[t][m][j];
        __syncthreads();
        float* outp = partials + (size_t)ks * (B_ * N_) + (size_t)bt * 2560;
        for (int f = tid; f < 2560; f += 256)
            outp[f] = red[f] + red[2560 + f] + red[5120 + f] + red[7680 + f];
    }

    // completion counters (device-scope release: fence by all, then barrier, then atomic)
    __threadfence();
    __syncthreads();
    if (tid == 0) {
        flags[0] = (atomicAdd(&cnt[bt0], 1) == KS_ - 1) ? 1 : 0;
        flags[1] = (atomicAdd(&cnt[bt0 + 8], 1) == KS_ - 1) ? 1 : 0;
    }
    __syncthreads();
#pragma unroll
    for (int t = 0; t < 2; ++t) {
        if (flags[t]) {
            __threadfence();   // acquire: see all 32 slices
            int bt = bt0 + 8 * t;
            for (int f = tid; f < 2560; f += 256) {
                int g = bt * 2560 + f;
                float s = 0.0f;
#pragma unroll
                for (int ksi = 0; ksi < KS_; ++ksi)
                    s += partials[(size_t)ksi * (B_ * N_) + g];
                s *= scale;
                float sq = s * s;
                dst[g] = sq / (1.0f + sq) * s / (sqrtf(sq) + 1e-5f);
            }
        }
    }
}

// bij[r][n] (+)= (1/B) * sum_b v[b][n] * tT[c][b][r];  nsum[n] += sum_r exp(bij)
__device__ void bupd_phase(const float* __restrict__ v, const float* __restrict__ tT,
                           float* __restrict__ bij, float* __restrict__ nsum,
                           int accumulate, int bid, int tid, float* __restrict__ smem) {
    if (bid >= 180) return;
    float* vs  = smem;          // [b][d] 4096
    float* red = smem + 4096;   // [d][tid] 4096
    int c = bid % 10;
    int r0 = (bid / 10) * 64;
    int rsub = tid & 63, bs = tid >> 6;

    for (int q = tid; q < 1024; q += 256) {
        int b = q >> 2, d4 = q & 3;
        ((float4*)vs)[q] = *(const float4*)(v + (size_t)b * N_ + c * 16 + d4 * 4);
    }
    __syncthreads();

    float acc[16];
#pragma unroll
    for (int d = 0; d < 16; ++d) acc[d] = 0.0f;

    const float* tp = tT + ((size_t)c * B_ + bs * 64) * R_ + r0 + rsub;
    for (int bb = 0; bb < 64; ++bb) {
        float tv = tp[(size_t)bb * R_];
        const float4* vrow = (const float4*)(vs + (bs * 64 + bb) * 16);
        float4 v0 = vrow[0], v1 = vrow[1], v2 = vrow[2], v3 = vrow[3];
        acc[0]  = fmaf(tv, v0.x, acc[0]);  acc[1]  = fmaf(tv, v0.y, acc[1]);
        acc[2]  = fmaf(tv, v0.z, acc[2]);  acc[3]  = fmaf(tv, v0.w, acc[3]);
        acc[4]  = fmaf(tv, v1.x, acc[4]);  acc[5]  = fmaf(tv, v1.y, acc[5]);
        acc[6]  = fmaf(tv, v1.z, acc[6]);  acc[7]  = fmaf(tv, v1.w, acc[7]);
        acc[8]  = fmaf(tv, v2.x, acc[8]);  acc[9]  = fmaf(tv, v2.y, acc[9]);
        acc[10] = fmaf(tv, v2.z, acc[10]); acc[11] = fmaf(tv, v2.w, acc[11]);
        acc[12] = fmaf(tv, v3.x, acc[12]); acc[13] = fmaf(tv, v3.y, acc[13]);
        acc[14] = fmaf(tv, v3.z, acc[14]); acc[15] = fmaf(tv, v3.w, acc[15]);
    }
#pragma unroll
    for (int d = 0; d < 16; ++d) red[d * 256 + tid] = acc[d];
    __syncthreads();

#pragma unroll
    for (int j = 0; j < 4; ++j) {
        int q = tid + 256 * j;
        int rr = q & 63, d = q >> 6;            // d uniform per wave
        const float* rp = red + d * 256 + rr;
        float s = (rp[0] + rp[64] + rp[128] + rp[192]) * (1.0f / B_);
        int o = (r0 + rr) * N_ + c * 16 + d;
        if (accumulate) s += bij[o];
        bij[o] = s;
        float ex = __expf(s);                    // max-free: |bij| = O(1)
#pragma unroll
        for (int off = 32; off > 0; off >>= 1) ex += __shfl_down(ex, off, 64);
        if (rr == 0) atomicAdd(&nsum[c * 16 + d], ex);
    }
    __syncthreads();
}

// WT[k][n] = W[r][n][i] * exp(bij[r][n]) / nsum[n]
__device__ void wtmod_phase(const float* __restrict__ W, const float* __restrict__ bij,
                            const float* __restrict__ nsum, float* __restrict__ WT,
                            int gid) {
    for (int q = gid; q < 368640; q += TOT) {
        int k = q / (N_ / 4);
        int n4 = (q % (N_ / 4)) * 4;
        int r = k >> 3, i = k & 7;
        const float* wp = W + (size_t)r * (C_ * D_ * I_) + n4 * I_ + i;
        float4 bb = *(const float4*)(bij + (size_t)r * N_ + n4);
        float4 ss = *(const float4*)(nsum + n4);
        float4 o;
        o.x = wp[0]  * (__expf(bb.x) / ss.x);
        o.y = wp[8]  * (__expf(bb.y) / ss.y);
        o.z = wp[16] * (__expf(bb.z) / ss.z);
        o.w = wp[24] * (__expf(bb.w) / ss.w);
        ((float4*)WT)[q] = o;
    }
}

// ===========================================================================
// Cooperative mega-kernel: 256 blocks (1/CU), 7 grid.syncs
// ===========================================================================
__global__ __launch_bounds__(256, 1) void mega_kernel(const float* __restrict__ u,
                                                      const float* __restrict__ W,
                                                      float* __restrict__ out,
                                                      float* __restrict__ ws) {
    cg::grid_group grid = cg::this_grid();
    __shared__ float smem[10240];   // 40 KB arena: gemm red / bupd vs+red
    __shared__ int flags[2];

    float* WT       = ws + OFF_WT;
    float* Wsum     = ws + OFF_WSUM;
    float* tT       = ws + OFF_TT;
    float* v        = ws + OFF_V;
    float* bij      = ws + OFF_BIJ;
    float* nsum     = ws + OFF_NSUM;
    float* partials = ws + OFF_PART;
    int*   cnt      = (int*)(ws + OFF_CNT);

    int bid = blockIdx.x, tid = threadIdx.x;
    int gid = bid * NTHR + tid;

    // A: setup (Wsum + WT0) + zero counters/nsum
    prep_phase(W, Wsum, WT, gid);
    if (gid < 48) cnt[gid] = 0;
    if (gid < N_) nsum[gid] = 0.0f;
    grid.sync();

    // B: gemm iter0 (lastblock -> v, scale 1/1152) + tT
    gemm_phase2(u, WT, partials, smem, cnt + 0, v, 1.0f / 1152.0f, bid, tid, flags);
    t_phase(u, Wsum, tT, gid);
    grid.sync();

    // D: bij = mean_b(v*t); nsum = sum_r exp(bij)
    bupd_phase(v, tT, bij, nsum, 0, bid, tid, smem);
    grid.sync();

    // E: WT = W * softmax(bij)
    wtmod_phase(W, bij, nsum, WT, gid);
    grid.sync();

    // F: gemm iter1 (lastblock -> v) + re-zero nsum (E already consumed it)
    if (gid < N_) nsum[gid] = 0.0f;
    gemm_phase2(u, WT, partials, smem, cnt + 16, v, 1.0f, bid, tid, flags);
    grid.sync();

    // H: bij += mean_b(v*t); nsum
    bupd_phase(v, tT, bij, nsum, 1, bid, tid, smem);
    grid.sync();

    // I: WT = W * softmax(bij)
    wtmod_phase(W, bij, nsum, WT, gid);
    grid.sync();

    // J: gemm iter2 (lastblock -> squash straight to out)
    gemm_phase2(u, WT, partials, smem, cnt + 32, out, 1.0f, bid, tid, flags);
}

// ===========================================================================
// Fallback path: proven round-2 multi-kernel sequence (215 us)
// ===========================================================================

__global__ void fb_prep_kernel(const float* __restrict__ W, float* __restrict__ Wsum,
                               float* __restrict__ WT) {
    if (blockIdx.x < 360) {
        int idx = blockIdx.x * 256 + threadIdx.x;
        int r = idx / (C_ * I_);
        int rem = idx % (C_ * I_);
        int c = rem / I_;
        int i = rem % I_;
        const float* p = W + (size_t)r * (C_ * D_ * I_) + c * (D_ * I_) + i;
        float s = 0.0f;
#pragma unroll
        for (int d = 0; d < D_; ++d) s += p[d * I_];
        Wsum[idx] = s;
    } else {
        int q = (blockIdx.x - 360) * 256 + threadIdx.x;
        int k = q / (N_ / 4);
        int n4 = (q % (N_ / 4)) * 4;
        int r = k >> 3, i = k & 7;
        const float* wp = W + (size_t)r * (C_ * D_ * I_) + n4 * I_ + i;
        float4 o;
        o.x = wp[0]; o.y = wp[8]; o.z = wp[16]; o.w = wp[24];
        ((float4*)WT)[q] = o;
    }
}

__global__ void fb_t_kernel(const float* __restrict__ u, const float* __restrict__ Wsum,
                            float* __restrict__ tT) {
    int idx = blockIdx.x * 256 + threadIdx.x;
    int r = idx % R_;
    int b = idx / R_;
    const float4* up = (const float4*)(u + (size_t)idx * I_);
    float4 a0 = up[0], a1 = up[1];
    const float* wp = Wsum + (size_t)r * (C_ * I_);
    float outv[C_];
#pragma unroll
    for (int c = 0; c < C_; ++c) {
        const float4* w4 = (const float4*)(wp + c * I_);
        float4 w0 = w4[0], w1 = w4[1];
        outv[c] = a0.x * w0.x + a0.y * w0.y + a0.z * w0.z + a0.w * w0.w
                + a1.x * w1.x + a1.y * w1.y + a1.z * w1.z + a1.w * w1.w;
    }
#pragma unroll
    for (int c = 0; c < C_; ++c)
        tT[((size_t)c * B_ + b) * R_ + r] = outv[c];
}

__global__ void fb_wtmod_kernel(const float* __restrict__ W, const float* __restrict__ bij,
                                const float* __restrict__ nmax, const float* __restrict__ nsum,
                                float* __restrict__ WT) {
    int q = blockIdx.x * 256 + threadIdx.x;
    int k = q / (N_ / 4);
    int n4 = (q % (N_ / 4)) * 4;
    int r = k >> 3, i = k & 7;
    const float* wp = W + (size_t)r * (C_ * D_ * I_) + n4 * I_ + i;
    float4 bb = *(const float4*)(bij + (size_t)r * N_ + n4);
    float4 mm = *(const float4*)(nmax + n4);
    float4 ss = *(const float4*)(nsum + n4);
    float4 o;
    o.x = wp[0]  * (__expf(bb.x - mm.x) / ss.x);
    o.y = wp[8]  * (__expf(bb.y - mm.y) / ss.y);
    o.z = wp[16] * (__expf(bb.z - mm.z) / ss.z);
    o.w = wp[24] * (__expf(bb.w - mm.w) / ss.w);
    ((float4*)WT)[q] = o;
}

__launch_bounds__(256)
__global__ void fb_gemm_kernel(const float* __restrict__ u, const float* __restrict__ WT,
                               float* __restrict__ partials) {
    __shared__ float red[4 * 2560];
    int tid = threadIdx.x;
    int wave = tid >> 6, lane = tid & 63;
    int ng = lane & 15, bg = lane >> 4;
    int b0 = blockIdx.y * 16;
    int kbase = blockIdx.x * KC_ + wave * KW_;
    int n0 = ng * 10;

    float acc[4][10];
#pragma unroll
    for (int m = 0; m < 4; ++m)
#pragma unroll
        for (int j = 0; j < 10; ++j) acc[m][j] = 0.0f;

    const float* ur[4];
#pragma unroll
    for (int m = 0; m < 4; ++m) ur[m] = u + (size_t)(b0 + bg * 4 + m) * K_;

    for (int kk = 0; kk < KW_; kk += 4) {
        int k = kbase + kk;
        float ua[4][4];
#pragma unroll
        for (int m = 0; m < 4; ++m) {
            float4 tmp = *(const float4*)(ur[m] + k);
            ua[m][0] = tmp.x; ua[m][1] = tmp.y; ua[m][2] = tmp.z; ua[m][3] = tmp.w;
        }
#pragma unroll
        for (int t4 = 0; t4 < 4; ++t4) {
            const float* wrow = WT + (size_t)(k + t4) * N_ + n0;
            float w[10];
#pragma unroll
            for (int j = 0; j < 10; j += 2) {
                float2 ww = *(const float2*)(wrow + j);
                w[j] = ww.x; w[j + 1] = ww.y;
            }
#pragma unroll
            for (int m = 0; m < 4; ++m)
#pragma unroll
                for (int j = 0; j < 10; ++j)
                    acc[m][j] = fmaf(ua[m][t4], w[j], acc[m][j]);
        }
    }

#pragma unroll
    for (int m = 0; m < 4; ++m)
#pragma unroll
        for (int j = 0; j < 10; ++j)
            red[wave * 2560 + (bg * 4 + m) * N_ + n0 + j] = acc[m][j];
    __syncthreads();
    float* outp = partials + (size_t)blockIdx.x * (B_ * N_) + (size_t)b0 * N_;
    for (int f = tid; f < 2560; f += 256)
        outp[f] = red[f] + red[2560 + f] + red[5120 + f] + red[7680 + f];
}

__global__ void fb_reduce_squash_kernel(const float* __restrict__ partials,
                                        float* __restrict__ dst, float scale) {
    int g = blockIdx.x * 256 + threadIdx.x;
    float s = 0.0f;
#pragma unroll
    for (int ks = 0; ks < KS_; ++ks) s += partials[(size_t)ks * (B_ * N_) + g];
    s *= scale;
    float sq = s * s;
    dst[g] = sq / (1.0f + sq) * s / (sqrtf(sq) + 1e-5f);
}

__launch_bounds__(256)
__global__ void fb_bupdate_kernel(const float* __restrict__ v, const float* __restrict__ tT,
                                  float* __restrict__ bij, int accumulate) {
    __shared__ float vs[B_ * 16];
    __shared__ float red[16 * 256];
    int tid = threadIdx.x;
    int c = blockIdx.y;
    int r0 = blockIdx.x * 64;
    int rsub = tid & 63, bs = tid >> 6;

    for (int q = tid; q < 1024; q += 256) {
        int b = q >> 2, d4 = q & 3;
        ((float4*)vs)[q] = *(const float4*)(v + (size_t)b * N_ + c * 16 + d4 * 4);
    }
    __syncthreads();

    float acc[16];
#pragma unroll
    for (int d = 0; d < 16; ++d) acc[d] = 0.0f;

    const float* tp = tT + ((size_t)c * B_ + bs * 64) * R_ + r0 + rsub;
    for (int bb = 0; bb < 64; ++bb) {
        float tv = tp[(size_t)bb * R_];
        const float4* vrow = (const float4*)(vs + (bs * 64 + bb) * 16);
        float4 v0 = vrow[0], v1 = vrow[1], v2 = vrow[2], v3 = vrow[3];
        acc[0]  = fmaf(tv, v0.x, acc[0]);  acc[1]  = fmaf(tv, v0.y, acc[1]);
        acc[2]  = fmaf(tv, v0.z, acc[2]);  acc[3]  = fmaf(tv, v0.w, acc[3]);
        acc[4]  = fmaf(tv, v1.x, acc[4]);  acc[5]  = fmaf(tv, v1.y, acc[5]);
        acc[6]  = fmaf(tv, v1.z, acc[6]);  acc[7]  = fmaf(tv, v1.w, acc[7]);
        acc[8]  = fmaf(tv, v2.x, acc[8]);  acc[9]  = fmaf(tv, v2.y, acc[9]);
        acc[10] = fmaf(tv, v2.z, acc[10]); acc[11] = fmaf(tv, v2.w, acc[11]);
        acc[12] = fmaf(tv, v3.x, acc[12]); acc[13] = fmaf(tv, v3.y, acc[13]);
        acc[14] = fmaf(tv, v3.z, acc[14]); acc[15] = fmaf(tv, v3.w, acc[15]);
    }
#pragma unroll
    for (int d = 0; d < 16; ++d) red[d * 256 + tid] = acc[d];
    __syncthreads();

    for (int q = tid; q < 1024; q += 256) {
        int rr = q & 63, d = q >> 6;
        const float* rp = red + d * 256 + rr;
        float s = (rp[0] + rp[64] + rp[128] + rp[192]) * (1.0f / B_);
        int o = (r0 + rr) * N_ + c * 16 + d;
        bij[o] = accumulate ? (bij[o] + s) : s;
    }
}

__global__ void fb_colstat_kernel(const float* __restrict__ bij,
                                  float* __restrict__ nmax, float* __restrict__ nsum) {
    int n = blockIdx.x;
    int tid = threadIdx.x;
    __shared__ float wred[4], wred2[4];
    float mx = -1e30f;
    for (int r = tid; r < R_; r += 256) mx = fmaxf(mx, bij[r * N_ + n]);
#pragma unroll
    for (int off = 32; off > 0; off >>= 1) mx = fmaxf(mx, __shfl_down(mx, off, 64));
    if ((tid & 63) == 0) wred[tid >> 6] = mx;
    __syncthreads();
    mx = fmaxf(fmaxf(wred[0], wred[1]), fmaxf(wred[2], wred[3]));
    float s = 0.0f;
    for (int r = tid; r < R_; r += 256) s += __expf(bij[r * N_ + n] - mx);
#pragma unroll
    for (int off = 32; off > 0; off >>= 1) s += __shfl_down(s, off, 64);
    if ((tid & 63) == 0) wred2[tid >> 6] = s;
    __syncthreads();
    if (tid == 0) {
        nmax[n] = mx;
        nsum[n] = wred2[0] + wred2[1] + wred2[2] + wred2[3];
    }
}

// ===========================================================================
extern "C" void kernel_launch(void* const* d_in, const int* in_sizes, int n_in,
                              void* d_out, int out_size, void* d_ws, size_t ws_size,
                              hipStream_t stream) {
    (void)in_sizes; (void)n_in; (void)out_size; (void)ws_size;
    const float* u = (const float*)d_in[0];
    const float* W = (const float*)d_in[1];
    float* out = (float*)d_out;
    float* ws = (float*)d_ws;

    // host-only prechecks (graph-capture safe: nothing touches the stream)
    int dev = 0;
    (void)hipGetDevice(&dev);
    int coop = 0;
    (void)hipDeviceGetAttribute(&coop, hipDeviceAttributeCooperativeLaunch, dev);
    int ncu = 0;
    (void)hipDeviceGetAttribute(&ncu, hipDeviceAttributeMultiprocessorCount, dev);
    int maxb = 0;
    (void)hipOccupancyMaxActiveBlocksPerMultiprocessor(
        &maxb, reinterpret_cast<const void*>(mega_kernel), NTHR, 0);

    if (coop != 0 && maxb > 0 && (long)maxb * ncu >= NBLK) {
        void* args[] = {(void*)&u, (void*)&W, (void*)&out, (void*)&ws};
        hipError_t e = hipLaunchCooperativeKernel(
            reinterpret_cast<const void*>(mega_kernel), dim3(NBLK), dim3(NTHR),
            args, 0, stream);
        if (e == hipSuccess) return;
        (void)hipGetLastError();   // clear sticky error, fall through
    }

    // fallback: proven multi-kernel path
    float* WT       = ws + OFF_WT;
    float* Wsum     = ws + OFF_WSUM;
    float* tT       = ws + OFF_TT;
    float* v        = ws + OFF_V;
    float* bij      = ws + OFF_BIJ;
    float* nmax     = ws + OFF_NMAX;
    float* nsum     = ws + OFF_NSUM;
    float* partials = ws + OFF_PART;

    fb_prep_kernel<<<1800, 256, 0, stream>>>(W, Wsum, WT);
    fb_t_kernel<<<1152, 256, 0, stream>>>(u, Wsum, tT);

    for (int iter = 0; iter < 3; ++iter) {
        fb_gemm_kernel<<<dim3(KS_, 16), 256, 0, stream>>>(u, WT, partials);
        fb_reduce_squash_kernel<<<160, 256, 0, stream>>>(
            partials, (iter == 2) ? out : v, (iter == 0) ? (1.0f / 1152.0f) : 1.0f);
        if (iter < 2) {
            fb_bupdate_kernel<<<dim3(18, 10), 256, 0, stream>>>(v, tT, bij, iter);
            fb_colstat_kernel<<<160, 256, 0, stream>>>(bij, nmax, nsum);
            fb_wtmod_kernel<<<1440, 256, 0, stream>>>(W, bij, nmax, nsum, WT);
        }
    }
}